// Round 1
// baseline (18996.782 us; speedup 1.0000x reference)
//
// LSTM_42030549958804 — persistent group-synced bf16-MFMA LSTM for MI355X (gfx950)
//
// R1 design notes:
//  - 1024 sequential steps => latency-bound. Persistent kernels (1 per layer),
//    8 independent batch-groups x 32 WGs, group-local barrier per step via
//    agent-scope atomics (+__threadfence for cross-XCD L2 visibility).
//  - Weights live in LDS per WG for all 512 steps (loaded once, fragment-packed).
//  - All bf16 operands pre-swizzled to mfma_f32_16x16x32_bf16 fragment order:
//      A: m=lane&15, k=(lane>>4)*8+j   (m120-verified)
//      D: col=lane&15, row=(lane>>4)*4+reg (m89-verified)
//    k-permutation self-cancels between A-pack and B-pack.
//  - fp32 c-state in registers, fp32 accum; bf16 only at matmul inputs.

#include <hip/hip_runtime.h>
#include <cstdint>
#include <cstddef>

#define B_  256
#define T_  512
#define I_  256
#define H_  512

typedef unsigned short u16;
typedef __bf16 bf16x8 __attribute__((ext_vector_type(8)));
typedef float f32x4 __attribute__((ext_vector_type(4)));

__device__ __forceinline__ u16 f2bf(float x) {
  union { float f; unsigned int u; } v; v.f = x;
  unsigned int r = (v.u + 0x7fffu + ((v.u >> 16) & 1u)) >> 16;
  return (u16)r;
}
__device__ __forceinline__ float sigm(float x) { return 1.0f / (1.0f + __expf(-x)); }
__device__ __forceinline__ float tanh_(float x) {
  float e = __expf(2.0f * x);
  return 1.0f - 2.0f / (e + 1.0f);   // -> -1 for x<<0, +1 for x>>0, no NaN
}

// ---------------- group barrier (32 WGs sharing one batch tile) ----------------
__device__ __forceinline__ void group_arrive(unsigned int* cntp, unsigned int* genp, int t) {
  __threadfence();  // flush this XCD L2 so our h-writes are LLC-visible
  unsigned int old = __hip_atomic_fetch_add(cntp, 1u, __ATOMIC_ACQ_REL, __HIP_MEMORY_SCOPE_AGENT);
  if (old == 31u) {
    __hip_atomic_store(cntp, 0u, __ATOMIC_RELAXED, __HIP_MEMORY_SCOPE_AGENT);
    __hip_atomic_store(genp, (unsigned int)(t + 1), __ATOMIC_RELEASE, __HIP_MEMORY_SCOPE_AGENT);
  }
}
__device__ __forceinline__ void group_wait(const unsigned int* genp, int t) {
  unsigned int it = 0;
  while (__hip_atomic_load(genp, __ATOMIC_RELAXED, __HIP_MEMORY_SCOPE_AGENT) < (unsigned int)t) {
    __builtin_amdgcn_s_sleep(2);
    if (++it > (1u << 26)) break;  // bail out instead of wedging the device
  }
  __threadfence();  // invalidate L1/L2 so h-reads see other WGs' stores
}

// ---------------- weight pack: [Wih | Whh] -> fragment-ordered bf16 ----------------
// packed col pc = unit*4 + gate (gate order i,f,g,o = orig rows g*512+u)
// dst halves: ((c16*KC + kc)*64 + lane)*8 + j ; lane=(q<<4)|(pc&15), k=kc*32+q*8+j
template<int KXC>
__global__ void pack_w(const float* __restrict__ Wih, const float* __restrict__ Whh,
                       const float* __restrict__ bih, const float* __restrict__ bhh,
                       u16* __restrict__ Wp, float* __restrict__ bp)
{
  constexpr int KC = KXC + 16;
  constexpr int KX = KXC * 32;
  const int total = 2048 * KC * 4;          // 16B groups
  int gid = blockIdx.x * 256 + threadIdx.x;
  if (gid < 2048) {
    int gg = gid & 3, u = gid >> 2;
    bp[gid] = bih[gg * 512 + u] + bhh[gg * 512 + u];
  }
  if (gid >= total) return;
  int lane = gid & 63;
  int tmp  = gid >> 6;
  int kc   = tmp % KC;
  int c16  = tmp / KC;
  int pc   = c16 * 16 + (lane & 15);
  int k0   = kc * 32 + (lane >> 4) * 8;
  int gg = pc & 3, u = pc >> 2;
  int row = gg * 512 + u;
  union { u16 v[8]; uint4 q; } out;
#pragma unroll
  for (int j = 0; j < 8; ++j) {
    int k = k0 + j;
    float f = (k < KX) ? Wih[(size_t)row * KX + k] : Whh[(size_t)row * 512 + (k - KX)];
    out.v[j] = f2bf(f);
  }
  *(uint4*)(Wp + (size_t)gid * 8) = out.q;
}

// ---------------- X fp32 [B,T,I] -> bf16 fragment-ordered [t][b16][kc][lane][8] ----------------
__global__ void pack_x(const float* __restrict__ X, u16* __restrict__ Xp)
{
  int gid = blockIdx.x * 256 + threadIdx.x;  // total = 256*512*256/8 = 4194304, exact grid
  int lane = gid & 63;
  int tmp  = gid >> 6;
  int kc   = tmp & 7;
  int tmp2 = tmp >> 3;
  int b16  = tmp2 & 15;
  int t    = tmp2 >> 4;
  int b  = b16 * 16 + (lane & 15);
  int i0 = kc * 32 + (lane >> 4) * 8;
  const float* src = X + ((size_t)b * T_ + t) * I_ + i0;
  float4 f0 = *(const float4*)src;
  float4 f1 = *(const float4*)(src + 4);
  union { u16 v[8]; uint4 q; } out;
  out.v[0] = f2bf(f0.x); out.v[1] = f2bf(f0.y); out.v[2] = f2bf(f0.z); out.v[3] = f2bf(f0.w);
  out.v[4] = f2bf(f1.x); out.v[5] = f2bf(f1.y); out.v[6] = f2bf(f1.z); out.v[7] = f2bf(f1.w);
  *(uint4*)(Xp + (size_t)gid * 8) = out.q;
}

// ---------------- persistent LSTM layer ----------------
// grid 256 (g = bid&7 batch tile of 32, w64 = bid>>3 col tile of 64 packed cols = 16 units)
// block 256 (4 waves, wave w owns 16-col subtile w)
template<int KXC, bool ISL0>
__global__ __launch_bounds__(256, 1) void lstm_layer(
    const u16* __restrict__ Wp, const float* __restrict__ bp,
    const u16* __restrict__ Xsrc, u16* __restrict__ H0dst,
    u16* __restrict__ Hbuf, float* __restrict__ hlast,
    unsigned int* syncbase)
{
  constexpr int KC = KXC + 16;
  extern __shared__ u16 smem[];
  u16*   Wlds = smem;                        // 4*KC*512 halves, fragment order
  float* gbuf = (float*)(smem + 4 * KC * 512); // 32 x 64 gates, padded stride 68

  const int tid  = threadIdx.x;
  const int lane = tid & 63;
  const int wave = tid >> 6;
  const int bid  = blockIdx.x;
  const int g    = bid & 7;
  const int w64  = bid >> 3;

  unsigned int* cntp = syncbase + g * 64;
  unsigned int* genp = cntp + 32;

  // ---- stage this WG's weight slice into LDS (once) ----
  {
    const u16* src = Wp + (size_t)w64 * 4 * KC * 512;
    for (int off = tid * 8; off < 4 * KC * 512; off += 256 * 8)
      *(uint4*)(Wlds + off) = *(const uint4*)(src + off);
  }
  __syncthreads();

  const u16* wbase = Wlds + wave * (KC * 512) + lane * 8;

  // pointwise ownership: pair0 = (row r0p, unit u0), pair1 = (r0p+16, u0)
  const int u0  = tid & 15;
  const int r0p = tid >> 4;
  const float4 bb = *(const float4*)(bp + w64 * 64 + u0 * 4);
  float c0 = 0.f, c1 = 0.f;

  for (int t = 0; t < T_; ++t) {
    f32x4 acc0 = {0.f, 0.f, 0.f, 0.f};
    f32x4 acc1 = {0.f, 0.f, 0.f, 0.f};

    // ---- x segment (barrier-independent: overlaps group stragglers) ----
    {
      const u16* xs = Xsrc + ((size_t)t * 16 + g * 2) * (KXC * 512) + lane * 8;
      const u16* wk = wbase;
#pragma unroll 4
      for (int kc = 0; kc < KXC; ++kc) {
        bf16x8 a0 = *(const bf16x8*)(xs + kc * 512);
        bf16x8 a1 = *(const bf16x8*)(xs + KXC * 512 + kc * 512);
        bf16x8 bw = *(const bf16x8*)(wk + kc * 512);
        acc0 = __builtin_amdgcn_mfma_f32_16x16x32_bf16(a0, bw, acc0, 0, 0, 0);
        acc1 = __builtin_amdgcn_mfma_f32_16x16x32_bf16(a1, bw, acc1, 0, 0, 0);
      }
    }

    // ---- wait for group's h(t-1), then h segment ----
    if (t > 0) {
      if (tid == 0) group_wait(genp, t);
      __syncthreads();
      const u16* hs = Hbuf + (size_t)(t & 1) * (B_ * H_) + g * (2 * 16 * 512) + lane * 8;
      const u16* wk = wbase + KXC * 512;
#pragma unroll 4
      for (int kc = 0; kc < 16; ++kc) {
        bf16x8 a0 = *(const bf16x8*)(hs + kc * 512);
        bf16x8 a1 = *(const bf16x8*)(hs + 16 * 512 + kc * 512);
        bf16x8 bw = *(const bf16x8*)(wk + kc * 512);
        acc0 = __builtin_amdgcn_mfma_f32_16x16x32_bf16(a0, bw, acc0, 0, 0, 0);
        acc1 = __builtin_amdgcn_mfma_f32_16x16x32_bf16(a1, bw, acc1, 0, 0, 0);
      }
    }

    // ---- spill gates to LDS (D frag: col=lane&15, row=(lane>>4)*4+r) ----
    {
      int rr = (lane >> 4) * 4;
      int cc = wave * 16 + (lane & 15);
#pragma unroll
      for (int r = 0; r < 4; ++r) {
        gbuf[(rr + r) * 68 + cc]      = acc0[r];
        gbuf[(16 + rr + r) * 68 + cc] = acc1[r];
      }
    }
    __syncthreads();

    // ---- pointwise LSTM cell (2 (row,unit) pairs per thread) ----
#pragma unroll
    for (int pp = 0; pp < 2; ++pp) {
      int r = r0p + pp * 16;
      float4 gv = *(const float4*)(gbuf + r * 68 + u0 * 4);
      float ii = sigm(gv.x + bb.x);
      float ff = sigm(gv.y + bb.y);
      float g2 = tanh_(gv.z + bb.z);
      float oo = sigm(gv.w + bb.w);
      float cprev = pp ? c1 : c0;
      float cnew = ff * cprev + ii * g2;
      if (pp) c1 = cnew; else c0 = cnew;
      float hh = oo * tanh_(cnew);

      int b = g * 32 + r;
      int j = w64 * 16 + u0;
      int b16 = b >> 4, bl = b & 15, kc = j >> 5, q = (j >> 3) & 3, jj = j & 7;
      u16 hb = f2bf(hh);
      int sw = (b16 * 16 + kc) * 512 + (q * 16 + bl) * 8 + jj;
      Hbuf[(size_t)((t + 1) & 1) * (B_ * H_) + sw] = hb;
      if (ISL0) {
        H0dst[((size_t)t * 16 + b16) * 8192 + kc * 512 + (q * 16 + bl) * 8 + jj] = hb;
      } else if (t == T_ - 1) {
        hlast[(size_t)b * H_ + j] = hh;
      }
    }
    __syncthreads();          // drain h-stores (vmcnt0 before s_barrier) + gbuf WAR
    if (tid == 0) group_arrive(cntp, genp, t);
  }
}

// ---------------- final projection y = hlast @ Wlin^T + b ----------------
__global__ void final_k(const float* __restrict__ hlast, const float* __restrict__ Wlin,
                        const float* __restrict__ blin, float* __restrict__ out)
{
  int b = blockIdx.x;
  int l = threadIdx.x;  // 64
  float s = 0.f;
#pragma unroll
  for (int j = l; j < H_; j += 64) s += hlast[(size_t)b * H_ + j] * Wlin[j];
#pragma unroll
  for (int off = 32; off > 0; off >>= 1) s += __shfl_down(s, off);
  if (l == 0) out[b] = s + blin[0];
}

extern "C" void kernel_launch(void* const* d_in, const int* in_sizes, int n_in,
                              void* d_out, int out_size, void* d_ws, size_t ws_size,
                              hipStream_t stream) {
  (void)in_sizes; (void)n_in; (void)out_size; (void)ws_size;
  const float* X    = (const float*)d_in[0];
  const float* Wih0 = (const float*)d_in[1];
  const float* Whh0 = (const float*)d_in[2];
  const float* bih0 = (const float*)d_in[3];
  const float* bhh0 = (const float*)d_in[4];
  const float* Wih1 = (const float*)d_in[5];
  const float* Whh1 = (const float*)d_in[6];
  const float* bih1 = (const float*)d_in[7];
  const float* bhh1 = (const float*)d_in[8];
  const float* Wlin = (const float*)d_in[9];
  const float* blin = (const float*)d_in[10];
  float* out = (float*)d_out;

  char* ws = (char*)d_ws;
  size_t o = 0;
  auto take = [&](size_t bytes) { char* p = ws + o; o = (o + bytes + 255) & ~(size_t)255; return p; };
  u16*   Wp0   = (u16*)take(2048ull * 768 * 2);            // 3 MB
  u16*   Wp1   = (u16*)take(2048ull * 1024 * 2);           // 4 MB
  float* bp0   = (float*)take(2048 * 4);
  float* bp1   = (float*)take(2048 * 4);
  u16*   Xsw   = (u16*)take((size_t)B_ * T_ * I_ * 2);     // 67 MB
  u16*   H0sw  = (u16*)take((size_t)B_ * T_ * H_ * 2);     // 134 MB
  u16*   Hbuf  = (u16*)take((size_t)2 * B_ * H_ * 2);      // 512 KB (double-buffered h)
  float* hlast = (float*)take((size_t)B_ * H_ * 4);        // 512 KB
  unsigned int* sync = (unsigned int*)take(4096);          // per-group padded cnt/gen

  hipMemsetAsync(sync, 0, 4096, stream);

  pack_w<8> <<<768,  256, 0, stream>>>(Wih0, Whh0, bih0, bhh0, Wp0, bp0);
  pack_w<16><<<1024, 256, 0, stream>>>(Wih1, Whh1, bih1, bhh1, Wp1, bp1);
  pack_x    <<<16384,256, 0, stream>>>(X, Xsw);

  auto k0 = lstm_layer<8,  true>;
  auto k1 = lstm_layer<16, false>;
  const int lds0 = 24 * 4096 + 68 * 32 * 4;   // 98304 + 8704 = 107008
  const int lds1 = 32 * 4096 + 68 * 32 * 4;   // 131072 + 8704 = 139776
  hipFuncSetAttribute(reinterpret_cast<const void*>(k0), hipFuncAttributeMaxDynamicSharedMemorySize, lds0);
  hipFuncSetAttribute(reinterpret_cast<const void*>(k1), hipFuncAttributeMaxDynamicSharedMemorySize, lds1);

  lstm_layer<8,  true> <<<256, 256, lds0, stream>>>(Wp0, bp0, Xsw,  H0sw,    Hbuf, nullptr, sync);
  lstm_layer<16, false><<<256, 256, lds1, stream>>>(Wp1, bp1, H0sw, nullptr, Hbuf, hlast,   sync + 512);
  final_k<<<256, 64, 0, stream>>>(hlast, Wlin, blin, out);
}

// Round 2
// 9838.689 us; speedup vs baseline: 1.9308x; 1.9308x over previous
//
// LSTM_42030549958804 — persistent group-synced bf16-MFMA LSTM for MI355X (gfx950)
//
// R2: barrier rebuild. R1 measured 18.9us/step with MfmaUtil=2.2% — the
// 32-WG same-address atomic RMW barrier serialized at the coherence point.
// Now: per-WG padded flag slots (release store, no RMW) + wave-parallel poll
// (32 flags in one load instruction), scoped acquire/release fences instead
// of seq-cst __threadfence. MFMA loops fully unrolled to hoist loads.
//
//  - 1024 sequential steps => latency-bound. Persistent kernels (1 per layer),
//    8 independent batch-groups x 32 WGs, group-local barrier per step.
//  - Weights live in LDS per WG for all 512 steps (loaded once, fragment-packed).
//  - All bf16 operands pre-swizzled to mfma_f32_16x16x32_bf16 fragment order:
//      A: m=lane&15, k=(lane>>4)*8+j ; D: col=lane&15, row=(lane>>4)*4+reg
//    k-permutation self-cancels between A-pack and B-pack.
//  - fp32 c-state in registers, fp32 accum; bf16 only at matmul inputs.

#include <hip/hip_runtime.h>
#include <cstdint>
#include <cstddef>

#define B_  256
#define T_  512
#define I_  256
#define H_  512

typedef unsigned short u16;
typedef __bf16 bf16x8 __attribute__((ext_vector_type(8)));
typedef float f32x4 __attribute__((ext_vector_type(4)));

__device__ __forceinline__ u16 f2bf(float x) {
  union { float f; unsigned int u; } v; v.f = x;
  unsigned int r = (v.u + 0x7fffu + ((v.u >> 16) & 1u)) >> 16;
  return (u16)r;
}
__device__ __forceinline__ float sigm(float x) { return 1.0f / (1.0f + __expf(-x)); }
__device__ __forceinline__ float tanh_(float x) {
  float e = __expf(2.0f * x);
  return 1.0f - 2.0f / (e + 1.0f);   // -> -1 for x<<0, +1 for x>>0, no NaN
}

// ---------------- group barrier (32 WGs sharing one batch tile) ----------------
// flags: one dword per WG, padded to 64B (16 dwords) to kill false sharing.
// Arrival: release-store generation t+1 into own slot (no RMW contention).
// Wait: lanes 0..31 of wave 0 poll all 32 slots in parallel (1 instr/round).
__device__ __forceinline__ void group_arrive(unsigned int* flags, int w64, int t) {
  __builtin_amdgcn_fence(__ATOMIC_RELEASE, "agent");   // wb L2: h-stores -> LLC
  __hip_atomic_store(flags + w64 * 16, (unsigned int)(t + 1),
                     __ATOMIC_RELAXED, __HIP_MEMORY_SCOPE_AGENT);
}
__device__ __forceinline__ void group_wait(const unsigned int* flags, int lane, int t) {
  const unsigned int* p = flags + (lane & 31) * 16;
  unsigned int it = 0;
  while (__hip_atomic_load(p, __ATOMIC_RELAXED, __HIP_MEMORY_SCOPE_AGENT) < (unsigned int)t) {
    __builtin_amdgcn_s_sleep(1);
    if (++it > (1u << 25)) break;  // bail out instead of wedging the device
  }
  __builtin_amdgcn_fence(__ATOMIC_ACQUIRE, "agent");   // inv L1/L2: see fresh h
}

// ---------------- weight pack: [Wih | Whh] -> fragment-ordered bf16 ----------------
// packed col pc = unit*4 + gate (gate order i,f,g,o = orig rows g*512+u)
// dst halves: ((c16*KC + kc)*64 + lane)*8 + j ; lane=(q<<4)|(pc&15), k=kc*32+q*8+j
template<int KXC>
__global__ void pack_w(const float* __restrict__ Wih, const float* __restrict__ Whh,
                       const float* __restrict__ bih, const float* __restrict__ bhh,
                       u16* __restrict__ Wp, float* __restrict__ bp)
{
  constexpr int KC = KXC + 16;
  constexpr int KX = KXC * 32;
  const int total = 2048 * KC * 4;          // 16B groups
  int gid = blockIdx.x * 256 + threadIdx.x;
  if (gid < 2048) {
    int gg = gid & 3, u = gid >> 2;
    bp[gid] = bih[gg * 512 + u] + bhh[gg * 512 + u];
  }
  if (gid >= total) return;
  int lane = gid & 63;
  int tmp  = gid >> 6;
  int kc   = tmp % KC;
  int c16  = tmp / KC;
  int pc   = c16 * 16 + (lane & 15);
  int k0   = kc * 32 + (lane >> 4) * 8;
  int gg = pc & 3, u = pc >> 2;
  int row = gg * 512 + u;
  union { u16 v[8]; uint4 q; } out;
#pragma unroll
  for (int j = 0; j < 8; ++j) {
    int k = k0 + j;
    float f = (k < KX) ? Wih[(size_t)row * KX + k] : Whh[(size_t)row * 512 + (k - KX)];
    out.v[j] = f2bf(f);
  }
  *(uint4*)(Wp + (size_t)gid * 8) = out.q;
}

// ---------------- X fp32 [B,T,I] -> bf16 fragment-ordered [t][b16][kc][lane][8] ----------------
__global__ void pack_x(const float* __restrict__ X, u16* __restrict__ Xp)
{
  int gid = blockIdx.x * 256 + threadIdx.x;  // total = 256*512*256/8 = 4194304, exact grid
  int lane = gid & 63;
  int tmp  = gid >> 6;
  int kc   = tmp & 7;
  int tmp2 = tmp >> 3;
  int b16  = tmp2 & 15;
  int t    = tmp2 >> 4;
  int b  = b16 * 16 + (lane & 15);
  int i0 = kc * 32 + (lane >> 4) * 8;
  const float* src = X + ((size_t)b * T_ + t) * I_ + i0;
  float4 f0 = *(const float4*)src;
  float4 f1 = *(const float4*)(src + 4);
  union { u16 v[8]; uint4 q; } out;
  out.v[0] = f2bf(f0.x); out.v[1] = f2bf(f0.y); out.v[2] = f2bf(f0.z); out.v[3] = f2bf(f0.w);
  out.v[4] = f2bf(f1.x); out.v[5] = f2bf(f1.y); out.v[6] = f2bf(f1.z); out.v[7] = f2bf(f1.w);
  *(uint4*)(Xp + (size_t)gid * 8) = out.q;
}

// ---------------- persistent LSTM layer ----------------
// grid 256 (g = bid&7 batch tile of 32, w64 = bid>>3 col tile of 64 packed cols = 16 units)
// block 256 (4 waves, wave w owns 16-col subtile w)
template<int KXC, bool ISL0>
__global__ __launch_bounds__(256, 1) void lstm_layer(
    const u16* __restrict__ Wp, const float* __restrict__ bp,
    const u16* __restrict__ Xsrc, u16* __restrict__ H0dst,
    u16* __restrict__ Hbuf, float* __restrict__ hlast,
    unsigned int* syncbase)
{
  constexpr int KC = KXC + 16;
  extern __shared__ u16 smem[];
  u16*   Wlds = smem;                        // 4*KC*512 halves, fragment order
  float* gbuf = (float*)(smem + 4 * KC * 512); // 32 x 64 gates, padded stride 68

  const int tid  = threadIdx.x;
  const int lane = tid & 63;
  const int wave = tid >> 6;
  const int bid  = blockIdx.x;
  const int g    = bid & 7;
  const int w64  = bid >> 3;

  unsigned int* gflags = syncbase + g * 512;  // 32 slots x 16 dwords

  // ---- stage this WG's weight slice into LDS (once) ----
  {
    const u16* src = Wp + (size_t)w64 * 4 * KC * 512;
    for (int off = tid * 8; off < 4 * KC * 512; off += 256 * 8)
      *(uint4*)(Wlds + off) = *(const uint4*)(src + off);
  }
  __syncthreads();

  const u16* wbase = Wlds + wave * (KC * 512) + lane * 8;

  // pointwise ownership: pair0 = (row r0p, unit u0), pair1 = (r0p+16, u0)
  const int u0  = tid & 15;
  const int r0p = tid >> 4;
  const float4 bb = *(const float4*)(bp + w64 * 64 + u0 * 4);
  float c0 = 0.f, c1 = 0.f;

  for (int t = 0; t < T_; ++t) {
    f32x4 acc0 = {0.f, 0.f, 0.f, 0.f};
    f32x4 acc1 = {0.f, 0.f, 0.f, 0.f};

    // ---- x segment (barrier-independent: overlaps group stragglers) ----
    {
      const u16* xs = Xsrc + ((size_t)t * 16 + g * 2) * (KXC * 512) + lane * 8;
      const u16* wk = wbase;
#pragma unroll
      for (int kc = 0; kc < KXC; ++kc) {
        bf16x8 a0 = *(const bf16x8*)(xs + kc * 512);
        bf16x8 a1 = *(const bf16x8*)(xs + KXC * 512 + kc * 512);
        bf16x8 bw = *(const bf16x8*)(wk + kc * 512);
        acc0 = __builtin_amdgcn_mfma_f32_16x16x32_bf16(a0, bw, acc0, 0, 0, 0);
        acc1 = __builtin_amdgcn_mfma_f32_16x16x32_bf16(a1, bw, acc1, 0, 0, 0);
      }
    }

    // ---- wait for group's h(t-1), then h segment ----
    if (t > 0) {
      if (tid < 64) group_wait(gflags, lane, t);
      __syncthreads();
      const u16* hs = Hbuf + (size_t)(t & 1) * (B_ * H_) + g * (2 * 16 * 512) + lane * 8;
      const u16* wk = wbase + KXC * 512;
#pragma unroll
      for (int kc = 0; kc < 16; ++kc) {
        bf16x8 a0 = *(const bf16x8*)(hs + kc * 512);
        bf16x8 a1 = *(const bf16x8*)(hs + 16 * 512 + kc * 512);
        bf16x8 bw = *(const bf16x8*)(wk + kc * 512);
        acc0 = __builtin_amdgcn_mfma_f32_16x16x32_bf16(a0, bw, acc0, 0, 0, 0);
        acc1 = __builtin_amdgcn_mfma_f32_16x16x32_bf16(a1, bw, acc1, 0, 0, 0);
      }
    }

    // ---- spill gates to LDS (D frag: col=lane&15, row=(lane>>4)*4+r) ----
    {
      int rr = (lane >> 4) * 4;
      int cc = wave * 16 + (lane & 15);
#pragma unroll
      for (int r = 0; r < 4; ++r) {
        gbuf[(rr + r) * 68 + cc]      = acc0[r];
        gbuf[(16 + rr + r) * 68 + cc] = acc1[r];
      }
    }
    __syncthreads();

    // ---- pointwise LSTM cell (2 (row,unit) pairs per thread) ----
#pragma unroll
    for (int pp = 0; pp < 2; ++pp) {
      int r = r0p + pp * 16;
      float4 gv = *(const float4*)(gbuf + r * 68 + u0 * 4);
      float ii = sigm(gv.x + bb.x);
      float ff = sigm(gv.y + bb.y);
      float g2 = tanh_(gv.z + bb.z);
      float oo = sigm(gv.w + bb.w);
      float cprev = pp ? c1 : c0;
      float cnew = ff * cprev + ii * g2;
      if (pp) c1 = cnew; else c0 = cnew;
      float hh = oo * tanh_(cnew);

      int b = g * 32 + r;
      int j = w64 * 16 + u0;
      int b16 = b >> 4, bl = b & 15, kc = j >> 5, q = (j >> 3) & 3, jj = j & 7;
      u16 hb = f2bf(hh);
      int sw = (b16 * 16 + kc) * 512 + (q * 16 + bl) * 8 + jj;
      Hbuf[(size_t)((t + 1) & 1) * (B_ * H_) + sw] = hb;
      if (ISL0) {
        H0dst[((size_t)t * 16 + b16) * 8192 + kc * 512 + (q * 16 + bl) * 8 + jj] = hb;
      } else if (t == T_ - 1) {
        hlast[(size_t)b * H_ + j] = hh;
      }
    }
    __syncthreads();          // drain h-stores (vmcnt0 before s_barrier) + gbuf WAR
    if (tid == 0) group_arrive(gflags, w64, t);
  }
}

// ---------------- final projection y = hlast @ Wlin^T + b ----------------
__global__ void final_k(const float* __restrict__ hlast, const float* __restrict__ Wlin,
                        const float* __restrict__ blin, float* __restrict__ out)
{
  int b = blockIdx.x;
  int l = threadIdx.x;  // 64
  float s = 0.f;
#pragma unroll
  for (int j = l; j < H_; j += 64) s += hlast[(size_t)b * H_ + j] * Wlin[j];
#pragma unroll
  for (int off = 32; off > 0; off >>= 1) s += __shfl_down(s, off);
  if (l == 0) out[b] = s + blin[0];
}

extern "C" void kernel_launch(void* const* d_in, const int* in_sizes, int n_in,
                              void* d_out, int out_size, void* d_ws, size_t ws_size,
                              hipStream_t stream) {
  (void)in_sizes; (void)n_in; (void)out_size; (void)ws_size;
  const float* X    = (const float*)d_in[0];
  const float* Wih0 = (const float*)d_in[1];
  const float* Whh0 = (const float*)d_in[2];
  const float* bih0 = (const float*)d_in[3];
  const float* bhh0 = (const float*)d_in[4];
  const float* Wih1 = (const float*)d_in[5];
  const float* Whh1 = (const float*)d_in[6];
  const float* bih1 = (const float*)d_in[7];
  const float* bhh1 = (const float*)d_in[8];
  const float* Wlin = (const float*)d_in[9];
  const float* blin = (const float*)d_in[10];
  float* out = (float*)d_out;

  char* ws = (char*)d_ws;
  size_t o = 0;
  auto take = [&](size_t bytes) { char* p = ws + o; o = (o + bytes + 255) & ~(size_t)255; return p; };
  u16*   Wp0   = (u16*)take(2048ull * 768 * 2);            // 3 MB
  u16*   Wp1   = (u16*)take(2048ull * 1024 * 2);           // 4 MB
  float* bp0   = (float*)take(2048 * 4);
  float* bp1   = (float*)take(2048 * 4);
  u16*   Xsw   = (u16*)take((size_t)B_ * T_ * I_ * 2);     // 67 MB
  u16*   H0sw  = (u16*)take((size_t)B_ * T_ * H_ * 2);     // 134 MB
  u16*   Hbuf  = (u16*)take((size_t)2 * B_ * H_ * 2);      // 512 KB (double-buffered h)
  float* hlast = (float*)take((size_t)B_ * H_ * 4);        // 512 KB
  unsigned int* sync = (unsigned int*)take(65536);         // 2 layers x 8 groups x 32 WG x 64B

  hipMemsetAsync(sync, 0, 65536, stream);

  pack_w<8> <<<768,  256, 0, stream>>>(Wih0, Whh0, bih0, bhh0, Wp0, bp0);
  pack_w<16><<<1024, 256, 0, stream>>>(Wih1, Whh1, bih1, bhh1, Wp1, bp1);
  pack_x    <<<16384,256, 0, stream>>>(X, Xsw);

  auto k0 = lstm_layer<8,  true>;
  auto k1 = lstm_layer<16, false>;
  const int lds0 = 24 * 4096 + 68 * 32 * 4;   // 98304 + 8704 = 107008
  const int lds1 = 32 * 4096 + 68 * 32 * 4;   // 131072 + 8704 = 139776
  hipFuncSetAttribute(reinterpret_cast<const void*>(k0), hipFuncAttributeMaxDynamicSharedMemorySize, lds0);
  hipFuncSetAttribute(reinterpret_cast<const void*>(k1), hipFuncAttributeMaxDynamicSharedMemorySize, lds1);

  lstm_layer<8,  true> <<<256, 256, lds0, stream>>>(Wp0, bp0, Xsw,  H0sw,    Hbuf, nullptr, sync);
  lstm_layer<16, false><<<256, 256, lds1, stream>>>(Wp1, bp1, H0sw, nullptr, Hbuf, hlast,   sync + 4096);
  final_k<<<256, 64, 0, stream>>>(hlast, Wlin, blin, out);
}

// Round 3
// 5370.400 us; speedup vs baseline: 3.5373x; 1.8320x over previous
//
// LSTM_42030549958804 — persistent group-synced bf16-MFMA LSTM for MI355X (gfx950)
//
// R3: fence elimination. R2 step=9.5us with per-step agent acquire(buffer_inv)
// + release(buffer_wbl2) fences wiping L1/L2 every step (FETCH_SIZE ~ full
// input re-stream confirmed). Now zero per-step cache maintenance:
//  - h stores: relaxed agent-scope atomic 8B stores (sc0 sc1, write-through to
//    LLC), wave0-only after LDS staging; release ordering = s_waitcnt vmcnt(0)
//    before the relaxed flag store. No wbl2.
//  - h loads: plain cached 16B loads on a ROTATING buffer (fresh addresses ->
//    cold L2 -> fetch from LLC; staleness impossible). Layer0 ring = full
//    T-depth and doubles as layer1's x input (kills the duplicate H0 stream).
//    Layer1 ring depth 64 + one acquire fence per 64 steps (amortized).
//  - X/weight loads stay cached and now persist in L2 across steps.
// Cross-replay stale-line hazard is benign: computation is deterministic, so
// stale clean lines hold identical bytes.
//
// Structure (from R1/R2): 8 batch-groups x 32 WGs, per-step group barrier via
// per-WG padded flags (release store + wave-parallel poll). Weights resident
// in LDS (fragment-packed). fp32 cell state; bf16 only at MFMA inputs.
// MFMA 16x16x32_bf16; A: m=lane&15,k=(lane>>4)*8+j; D: col=lane&15,row=(lane>>4)*4+reg.

#include <hip/hip_runtime.h>
#include <cstdint>
#include <cstddef>

#define B_  256
#define T_  512
#define I_  256
#define H_  512
#define RING 64

typedef unsigned short u16;
typedef unsigned long long u64;
typedef __bf16 bf16x8 __attribute__((ext_vector_type(8)));
typedef float f32x4 __attribute__((ext_vector_type(4)));

__device__ __forceinline__ u16 f2bf(float x) {
  union { float f; unsigned int u; } v; v.f = x;
  unsigned int r = (v.u + 0x7fffu + ((v.u >> 16) & 1u)) >> 16;
  return (u16)r;
}
__device__ __forceinline__ float sigm(float x) { return 1.0f / (1.0f + __expf(-x)); }
__device__ __forceinline__ float tanh_(float x) {
  float e = __expf(2.0f * x);
  return 1.0f - 2.0f / (e + 1.0f);
}

// ---------------- group barrier ----------------
// flags: one dword per WG, padded to 64B. Arrival: (in-kernel) vmcnt(0) then
// relaxed agent store of t+1. Wait: lanes 0..31 poll own slot (sc0 sc1 load,
// always fresh from LLC). Ordering for the subsequent h loads comes from the
// __syncthreads that follows (compiler + HW barrier).
__device__ __forceinline__ void group_wait(const unsigned int* flags, int lane, int t) {
  const unsigned int* p = flags + (lane & 31) * 16;
  unsigned int it = 0;
  while (__hip_atomic_load(p, __ATOMIC_RELAXED, __HIP_MEMORY_SCOPE_AGENT) < (unsigned int)t) {
    __builtin_amdgcn_s_sleep(1);
    if (++it > (1u << 25)) break;  // bail out instead of wedging the device
  }
}

// ---------------- weight pack: [Wih | Whh] -> fragment-ordered bf16 ----------------
template<int KXC>
__global__ void pack_w(const float* __restrict__ Wih, const float* __restrict__ Whh,
                       const float* __restrict__ bih, const float* __restrict__ bhh,
                       u16* __restrict__ Wp, float* __restrict__ bp)
{
  constexpr int KC = KXC + 16;
  constexpr int KX = KXC * 32;
  const int total = 2048 * KC * 4;          // 16B groups
  int gid = blockIdx.x * 256 + threadIdx.x;
  if (gid < 2048) {
    int gg = gid & 3, u = gid >> 2;
    bp[gid] = bih[gg * 512 + u] + bhh[gg * 512 + u];
  }
  if (gid >= total) return;
  int lane = gid & 63;
  int tmp  = gid >> 6;
  int kc   = tmp % KC;
  int c16  = tmp / KC;
  int pc   = c16 * 16 + (lane & 15);
  int k0   = kc * 32 + (lane >> 4) * 8;
  int gg = pc & 3, u = pc >> 2;
  int row = gg * 512 + u;
  union { u16 v[8]; uint4 q; } out;
#pragma unroll
  for (int j = 0; j < 8; ++j) {
    int k = k0 + j;
    float f = (k < KX) ? Wih[(size_t)row * KX + k] : Whh[(size_t)row * 512 + (k - KX)];
    out.v[j] = f2bf(f);
  }
  *(uint4*)(Wp + (size_t)gid * 8) = out.q;
}

// ---------------- X fp32 [B,T,I] -> bf16 fragment-ordered ----------------
__global__ void pack_x(const float* __restrict__ X, u16* __restrict__ Xp)
{
  int gid = blockIdx.x * 256 + threadIdx.x;  // total = 4194304, exact grid
  int lane = gid & 63;
  int tmp  = gid >> 6;
  int kc   = tmp & 7;
  int tmp2 = tmp >> 3;
  int b16  = tmp2 & 15;
  int t    = tmp2 >> 4;
  int b  = b16 * 16 + (lane & 15);
  int i0 = kc * 32 + (lane >> 4) * 8;
  const float* src = X + ((size_t)b * T_ + t) * I_ + i0;
  float4 f0 = *(const float4*)src;
  float4 f1 = *(const float4*)(src + 4);
  union { u16 v[8]; uint4 q; } out;
  out.v[0] = f2bf(f0.x); out.v[1] = f2bf(f0.y); out.v[2] = f2bf(f0.z); out.v[3] = f2bf(f0.w);
  out.v[4] = f2bf(f1.x); out.v[5] = f2bf(f1.y); out.v[6] = f2bf(f1.z); out.v[7] = f2bf(f1.w);
  *(uint4*)(Xp + (size_t)gid * 8) = out.q;
}

// ---------------- persistent LSTM layer ----------------
// grid 256: g = bid&7 (batch tile of 32), w64 = bid>>3 (64 packed cols = 16 units)
// FULL: h ring depth = T_ (layer0; doubles as next layer's x input).
// !FULL: ring depth RING, acquire fence every RING steps.
template<int KXC, bool FULL, bool LAST>
__global__ __launch_bounds__(256, 1) void lstm_layer(
    const u16* __restrict__ Wp, const float* __restrict__ bp,
    const u16* __restrict__ Xsrc, u16* __restrict__ Hdst,
    float* __restrict__ hlast, unsigned int* __restrict__ syncbase)
{
  constexpr int KC = KXC + 16;
  extern __shared__ u16 smem[];
  u16*   Wlds   = smem;                          // 4*KC*512 halves
  float* gbuf   = (float*)(smem + 4 * KC * 512); // 32 x 64 gates, stride 68
  u16*   hstage = (u16*)(gbuf + 68 * 32);        // 512 halves (1KB), 8B aligned

  const int tid  = threadIdx.x;
  const int lane = tid & 63;
  const int wave = tid >> 6;
  const int g    = blockIdx.x & 7;
  const int w64  = blockIdx.x >> 3;

  unsigned int* gflags = syncbase + g * 512;  // 32 slots x 16 dwords

  // ---- stage weight slice into LDS (once) ----
  {
    const u16* src = Wp + (size_t)w64 * 4 * KC * 512;
    for (int off = tid * 8; off < 4 * KC * 512; off += 256 * 8)
      *(uint4*)(Wlds + off) = *(const uint4*)(src + off);
  }
  __syncthreads();

  const u16* wbase = Wlds + wave * (KC * 512) + lane * 8;
  const int u0  = tid & 15;
  const int r0p = tid >> 4;
  const float4 bb = *(const float4*)(bp + w64 * 64 + u0 * 4);
  float c0 = 0.f, c1 = 0.f;

  // producer store geometry: units j = w64*16+u0 -> kc block, q range
  const int kcw = w64 >> 1;
  const int qlo = (2 * w64) & 3;

  for (int t = 0; t < T_; ++t) {
    f32x4 acc0 = {0.f, 0.f, 0.f, 0.f};
    f32x4 acc1 = {0.f, 0.f, 0.f, 0.f};

    // ---- x segment (cached loads; overlaps group stragglers) ----
    {
      const u16* xs = Xsrc + ((size_t)t * 16 + g * 2) * (KXC * 512) + lane * 8;
      const u16* wk = wbase;
#pragma unroll
      for (int kc = 0; kc < KXC; ++kc) {
        bf16x8 a0 = *(const bf16x8*)(xs + kc * 512);
        bf16x8 a1 = *(const bf16x8*)(xs + KXC * 512 + kc * 512);
        bf16x8 bw = *(const bf16x8*)(wk + kc * 512);
        acc0 = __builtin_amdgcn_mfma_f32_16x16x32_bf16(a0, bw, acc0, 0, 0, 0);
        acc1 = __builtin_amdgcn_mfma_f32_16x16x32_bf16(a1, bw, acc1, 0, 0, 0);
      }
    }

    // ---- wait for group's h(t-1), then h segment (plain cached loads on
    //      fresh ring addresses — data is at LLC, L2 cold => fresh) ----
    if (t > 0) {
      if (tid < 64) group_wait(gflags, lane, t);
      __syncthreads();
      if (!FULL && (t & (RING - 1)) == 0)
        __builtin_amdgcn_fence(__ATOMIC_ACQUIRE, "agent");  // ring reuse: drop 64-step-old lines
      const int slot_r = FULL ? (t - 1) : ((t - 1) & (RING - 1));
      const u16* hs = Hdst + (size_t)slot_r * 131072 + g * 16384 + lane * 8;
      const u16* wk = wbase + KXC * 512;
#pragma unroll
      for (int kc = 0; kc < 16; ++kc) {
        bf16x8 a0 = *(const bf16x8*)(hs + kc * 512);
        bf16x8 a1 = *(const bf16x8*)(hs + 16 * 512 + kc * 512);
        bf16x8 bw = *(const bf16x8*)(wk + kc * 512);
        acc0 = __builtin_amdgcn_mfma_f32_16x16x32_bf16(a0, bw, acc0, 0, 0, 0);
        acc1 = __builtin_amdgcn_mfma_f32_16x16x32_bf16(a1, bw, acc1, 0, 0, 0);
      }
    }

    // ---- spill gates to LDS (D frag: col=lane&15, row=(lane>>4)*4+r) ----
    {
      int rr = (lane >> 4) * 4;
      int cc = wave * 16 + (lane & 15);
#pragma unroll
      for (int r = 0; r < 4; ++r) {
        gbuf[(rr + r) * 68 + cc]      = acc0[r];
        gbuf[(16 + rr + r) * 68 + cc] = acc1[r];
      }
    }
    __syncthreads();

    // ---- pointwise LSTM cell -> stage h into LDS ----
#pragma unroll
    for (int pp = 0; pp < 2; ++pp) {
      int r = r0p + pp * 16;
      float4 gv = *(const float4*)(gbuf + r * 68 + u0 * 4);
      float ii = sigm(gv.x + bb.x);
      float ff = sigm(gv.y + bb.y);
      float g2 = tanh_(gv.z + bb.z);
      float oo = sigm(gv.w + bb.w);
      float cprev = pp ? c1 : c0;
      float cnew = ff * cprev + ii * g2;
      if (pp) c1 = cnew; else c0 = cnew;
      float hh = oo * tanh_(cnew);
      hstage[pp * 256 + (u0 >> 3) * 128 + r0p * 8 + (u0 & 7)] = f2bf(hh);
      if (LAST && t == T_ - 1)
        hlast[(size_t)(g * 32 + r) * H_ + (w64 * 16 + u0)] = hh;
    }
    __syncthreads();   // hstage ready (also protects gbuf WAR)

    // ---- wave0: write-through h to LLC, then flag (release via vmcnt0) ----
    if (tid < 64) {
      const size_t slot_w = (size_t)(FULL ? t : (t & (RING - 1))) * 131072;
      const size_t off    = slot_w + (size_t)qlo * 128 + lane * 4;
      u64 v0 = ((const u64*)hstage)[lane];
      u64 v1 = ((const u64*)hstage)[64 + lane];
      __hip_atomic_store((u64*)(Hdst + off + ((2 * g + 0) * 16 + kcw) * 512), v0,
                         __ATOMIC_RELAXED, __HIP_MEMORY_SCOPE_AGENT);
      __hip_atomic_store((u64*)(Hdst + off + ((2 * g + 1) * 16 + kcw) * 512), v1,
                         __ATOMIC_RELAXED, __HIP_MEMORY_SCOPE_AGENT);
      asm volatile("s_waitcnt vmcnt(0)" ::: "memory");  // h at LLC before flag
      if (tid == 0)
        __hip_atomic_store(gflags + w64 * 16, (unsigned int)(t + 1),
                           __ATOMIC_RELAXED, __HIP_MEMORY_SCOPE_AGENT);
    }
    // waves 1-3 run ahead into next step's x segment
  }
}

// ---------------- final projection y = hlast @ Wlin^T + b ----------------
__global__ void final_k(const float* __restrict__ hlast, const float* __restrict__ Wlin,
                        const float* __restrict__ blin, float* __restrict__ out)
{
  int b = blockIdx.x;
  int l = threadIdx.x;  // 64
  float s = 0.f;
#pragma unroll
  for (int j = l; j < H_; j += 64) s += hlast[(size_t)b * H_ + j] * Wlin[j];
#pragma unroll
  for (int off = 32; off > 0; off >>= 1) s += __shfl_down(s, off);
  if (l == 0) out[b] = s + blin[0];
}

extern "C" void kernel_launch(void* const* d_in, const int* in_sizes, int n_in,
                              void* d_out, int out_size, void* d_ws, size_t ws_size,
                              hipStream_t stream) {
  (void)in_sizes; (void)n_in; (void)out_size; (void)ws_size;
  const float* X    = (const float*)d_in[0];
  const float* Wih0 = (const float*)d_in[1];
  const float* Whh0 = (const float*)d_in[2];
  const float* bih0 = (const float*)d_in[3];
  const float* bhh0 = (const float*)d_in[4];
  const float* Wih1 = (const float*)d_in[5];
  const float* Whh1 = (const float*)d_in[6];
  const float* bih1 = (const float*)d_in[7];
  const float* bhh1 = (const float*)d_in[8];
  const float* Wlin = (const float*)d_in[9];
  const float* blin = (const float*)d_in[10];
  float* out = (float*)d_out;

  char* ws = (char*)d_ws;
  size_t o = 0;
  auto take = [&](size_t bytes) { char* p = ws + o; o = (o + bytes + 255) & ~(size_t)255; return p; };
  u16*   Wp0   = (u16*)take(2048ull * 768 * 2);              // 3 MB
  u16*   Wp1   = (u16*)take(2048ull * 1024 * 2);             // 4 MB
  float* bp0   = (float*)take(2048 * 4);
  float* bp1   = (float*)take(2048 * 4);
  u16*   Xsw   = (u16*)take((size_t)B_ * T_ * I_ * 2);       // 67 MB
  u16*   Hrot0 = (u16*)take((size_t)T_ * B_ * H_ * 2);       // 134 MB: layer0 h history = layer1 x
  u16*   Hring = (u16*)take((size_t)RING * B_ * H_ * 2);     // 16.8 MB: layer1 h ring
  float* hlast = (float*)take((size_t)B_ * H_ * 4);          // 512 KB
  unsigned int* sync = (unsigned int*)take(65536);           // 2 layers x 8 groups x 32 WG x 64B

  hipMemsetAsync(sync, 0, 65536, stream);

  pack_w<8> <<<768,  256, 0, stream>>>(Wih0, Whh0, bih0, bhh0, Wp0, bp0);
  pack_w<16><<<1024, 256, 0, stream>>>(Wih1, Whh1, bih1, bhh1, Wp1, bp1);
  pack_x    <<<16384,256, 0, stream>>>(X, Xsw);

  auto k0 = lstm_layer<8,  true,  false>;
  auto k1 = lstm_layer<16, false, true>;
  const int lds0 = 24 * 4096 + 68 * 32 * 4 + 1024;   // 98304 + 8704 + 1024 = 108032
  const int lds1 = 32 * 4096 + 68 * 32 * 4 + 1024;   // 131072 + 8704 + 1024 = 140800
  hipFuncSetAttribute(reinterpret_cast<const void*>(k0), hipFuncAttributeMaxDynamicSharedMemorySize, lds0);
  hipFuncSetAttribute(reinterpret_cast<const void*>(k1), hipFuncAttributeMaxDynamicSharedMemorySize, lds1);

  lstm_layer<8,  true,  false><<<256, 256, lds0, stream>>>(Wp0, bp0, Xsw,   Hrot0, nullptr, sync);
  lstm_layer<16, false, true ><<<256, 256, lds1, stream>>>(Wp1, bp1, Hrot0, Hring, hlast,   sync + 4096);
  final_k<<<256, 64, 0, stream>>>(hlast, Wlin, blin, out);
}

// Round 4
// 5196.212 us; speedup vs baseline: 3.6559x; 1.0335x over previous
//
// LSTM_42030549958804 — fused 2-layer persistent bf16-MFMA LSTM, MI355X (gfx950)
//
// R4: layer fusion + per-wave decoupling.
//  - One kernel, 512 WGs @ 2/CU (layer0 WG + layer1 WG per CU). Layer1 runs
//    1 step behind layer0; pipeline rate = max(step0, step1), not sum.
//  - Weights live in VGPRs (wx[KXC]+wh[16] bf16x8/lane, <=128 VGPR), not LDS.
//  - Layer0 steady loop has NO barriers: each wave owns 4 complete units
//    (all 4 gates), intra-wave LDS transpose (lgkmcnt only), per-lane c-state,
//    per-wave 8B write-through h store + per-wave flag (128 packed flags/group).
//  - Layer1: poll(f0>=t+1 & f1>=t) -> agent-load own h1 ring slot (depth 4,
//    agent loads dodge L2 staleness; staged via LDS to cut LLC traffic 4x),
//    overlapped with x-part MFMAs on h0(t) (plain cached, fresh Hrot0 slots).
//    Max group skew is 1 step (flag wait each step) => ring depth 4 safe.
//  - h stores: relaxed agent 8B (write-through to LLC); release = vmcnt(0)
//    before relaxed flag store. No cache-maintenance fences anywhere in loop.
// MFMA 16x16x32_bf16; A: m=lane&15,k=(lane>>4)*8+j; D: col=lane&15,row=(lane>>4)*4+reg.

#include <hip/hip_runtime.h>
#include <cstdint>
#include <cstddef>

#define B_  256
#define T_  512

typedef unsigned short u16;
typedef unsigned long long u64;
typedef __bf16 bf16x8 __attribute__((ext_vector_type(8)));
typedef float f32x4 __attribute__((ext_vector_type(4)));

#define AL32(p)   __hip_atomic_load((p),      __ATOMIC_RELAXED, __HIP_MEMORY_SCOPE_AGENT)
#define AL64(p)   __hip_atomic_load((p),      __ATOMIC_RELAXED, __HIP_MEMORY_SCOPE_AGENT)
#define AS32(p,v) __hip_atomic_store((p),(v), __ATOMIC_RELAXED, __HIP_MEMORY_SCOPE_AGENT)
#define AS64(p,v) __hip_atomic_store((p),(v), __ATOMIC_RELAXED, __HIP_MEMORY_SCOPE_AGENT)

__device__ __forceinline__ u16 f2bf(float x) {
  union { float f; unsigned int u; } v; v.f = x;
  unsigned int r = (v.u + 0x7fffu + ((v.u >> 16) & 1u)) >> 16;
  return (u16)r;
}
__device__ __forceinline__ float sigm(float x) { return 1.0f / (1.0f + __expf(-x)); }
__device__ __forceinline__ float tanh_(float x) {
  float e = __expf(2.0f * x);
  return 1.0f - 2.0f / (e + 1.0f);
}

// ---------------- group "barrier": 128 packed per-wave flags ----------------
__device__ __forceinline__ void poll1(const unsigned int* f, unsigned int need, int lane) {
  unsigned int it = 0;
  while (true) {
    unsigned int a = AL32(f + lane);
    unsigned int b = AL32(f + 64 + lane);
    if (__all(a >= need && b >= need)) break;
    __builtin_amdgcn_s_sleep(1);
    if (++it > (1u << 24)) break;  // bail instead of wedging the device
  }
}
__device__ __forceinline__ void poll2(const unsigned int* fp, unsigned int np,
                                      const unsigned int* fo, unsigned int no, int lane) {
  unsigned int it = 0;
  while (true) {
    unsigned int a = AL32(fp + lane);
    unsigned int b = AL32(fp + 64 + lane);
    unsigned int c = AL32(fo + lane);
    unsigned int d = AL32(fo + 64 + lane);
    if (__all(a >= np && b >= np && c >= no && d >= no)) break;
    __builtin_amdgcn_s_sleep(1);
    if (++it > (1u << 24)) break;
  }
}

// ---------------- weight pack: [Wih | Whh] -> fragment-ordered bf16 ----------------
// packed col pc = unit*4 + gate (gate order i,f,g,o); dst halves:
// ((c16*KC + kc)*64 + lane)*8 + j ; lane=(q<<4)|(pc&15), k=kc*32+q*8+j
template<int KXC>
__global__ void pack_w(const float* __restrict__ Wih, const float* __restrict__ Whh,
                       const float* __restrict__ bih, const float* __restrict__ bhh,
                       u16* __restrict__ Wp, float* __restrict__ bp)
{
  constexpr int KC = KXC + 16;
  constexpr int KX = KXC * 32;
  const int total = 2048 * KC * 4;          // 16B groups
  int gid = blockIdx.x * 256 + threadIdx.x;
  if (gid < 2048) {
    int gg = gid & 3, u = gid >> 2;
    bp[gid] = bih[gg * 512 + u] + bhh[gg * 512 + u];
  }
  if (gid >= total) return;
  int lane = gid & 63;
  int tmp  = gid >> 6;
  int kc   = tmp % KC;
  int c16  = tmp / KC;
  int pc   = c16 * 16 + (lane & 15);
  int k0   = kc * 32 + (lane >> 4) * 8;
  int gg = pc & 3, u = pc >> 2;
  int row = gg * 512 + u;
  union { u16 v[8]; uint4 q; } out;
#pragma unroll
  for (int j = 0; j < 8; ++j) {
    int k = k0 + j;
    float f = (k < KX) ? Wih[(size_t)row * KX + k] : Whh[(size_t)row * 512 + (k - KX)];
    out.v[j] = f2bf(f);
  }
  *(uint4*)(Wp + (size_t)gid * 8) = out.q;
}

// ---------------- X fp32 [B,T,I] -> bf16 fragment-ordered ----------------
__global__ void pack_x(const float* __restrict__ X, u16* __restrict__ Xp)
{
  int gid = blockIdx.x * 256 + threadIdx.x;  // total = 4194304, exact grid
  int lane = gid & 63;
  int tmp  = gid >> 6;
  int kc   = tmp & 7;
  int tmp2 = tmp >> 3;
  int b16  = tmp2 & 15;
  int t    = tmp2 >> 4;
  int b  = b16 * 16 + (lane & 15);
  int i0 = kc * 32 + (lane >> 4) * 8;
  const float* src = X + ((size_t)b * T_ + t) * 256 + i0;
  float4 f0 = *(const float4*)src;
  float4 f1 = *(const float4*)(src + 4);
  union { u16 v[8]; uint4 q; } out;
  out.v[0] = f2bf(f0.x); out.v[1] = f2bf(f0.y); out.v[2] = f2bf(f0.z); out.v[3] = f2bf(f0.w);
  out.v[4] = f2bf(f1.x); out.v[5] = f2bf(f1.y); out.v[6] = f2bf(f1.z); out.v[7] = f2bf(f1.w);
  *(uint4*)(Xp + (size_t)gid * 8) = out.q;
}

// ---------------- one layer's persistent loop (per wave) ----------------
// wave widx (0..127) of group g: units j = widx*4..widx*4+3, batch rows g*32..g*32+31.
template<int KXC, bool L1, bool LAST>
__device__ __forceinline__ void layer_loop(
    const u16* __restrict__ Wp, const float* __restrict__ bp,
    const u16* __restrict__ Xsrc, u16* __restrict__ Hdst,
    float* __restrict__ hlast,
    unsigned int* __restrict__ fown, const unsigned int* __restrict__ fprev,
    int g, int widx, int lane, int tid,
    float* gw, u16* hst, u64* hbuf)
{
  constexpr int KC = KXC + 16;
  // ---- weights -> registers ----
  bf16x8 wx[KXC], wh[16];
  const u16* wsrc = Wp + (size_t)widx * KC * 512 + lane * 8;
#pragma unroll
  for (int kc = 0; kc < KXC; ++kc) wx[kc] = *(const bf16x8*)(wsrc + kc * 512);
#pragma unroll
  for (int kc = 0; kc < 16; ++kc)  wh[kc] = *(const bf16x8*)(wsrc + (KXC + kc) * 512);

  const int uw = lane & 3, r0 = lane >> 2;      // pointwise ownership
  const int jb = widx * 4;
  const float4 bb = *(const float4*)(bp + (jb + uw) * 4);
  float c0 = 0.f, c1 = 0.f;
  const int kcb = widx >> 3, qq = (widx >> 1) & 3, jjb = (widx & 1) * 4;

  for (int t = 0; t < T_; ++t) {
    f32x4 acc0 = {0.f, 0.f, 0.f, 0.f};
    f32x4 acc1 = {0.f, 0.f, 0.f, 0.f};
    const u16* xs = Xsrc + ((size_t)t * 16 + g * 2) * (KXC * 512) + lane * 8;
    const int slot_r = L1 ? ((t - 1) & 3) : (t - 1);

    if (L1) {
      poll2(fprev, t + 1, fown, t, lane);   // h0(t) ready AND own group's h1(t-1)
      asm volatile("" ::: "memory");
    }

    // L1: issue own-h1 stage loads (agent: dodge stale L2 on ring reuse)
    u64 stg[16];
    if (L1 && t > 0) {
      const u64* src = (const u64*)(Hdst + (size_t)slot_r * 131072 + g * 16384);
#pragma unroll
      for (int i = 0; i < 16; ++i) stg[i] = AL64(src + i * 256 + tid);
    }

    // ---- x-part (layer0: Xsw; layer1: h0(t) from Hrot0, plain cached) ----
#pragma unroll
    for (int kc = 0; kc < KXC; ++kc) {
      bf16x8 a0 = *(const bf16x8*)(xs + kc * 512);
      bf16x8 a1 = *(const bf16x8*)(xs + (KXC + kc) * 512);
      acc0 = __builtin_amdgcn_mfma_f32_16x16x32_bf16(a0, wx[kc], acc0, 0, 0, 0);
      acc1 = __builtin_amdgcn_mfma_f32_16x16x32_bf16(a1, wx[kc], acc1, 0, 0, 0);
    }

    if (!L1 && t > 0) {
      poll1(fown, t, lane);                 // own group's h(t-1)
      asm volatile("" ::: "memory");
    }

    // ---- h-part ----
    if (t > 0) {
      if (!L1) {
        // fresh full-depth slots: plain cached b128 loads (L2-shared in group)
        const u16* hs = Hdst + (size_t)slot_r * 131072 + g * 16384 + lane * 8;
#pragma unroll
        for (int kc = 0; kc < 16; ++kc) {
          bf16x8 a0 = *(const bf16x8*)(hs + kc * 512);
          bf16x8 a1 = *(const bf16x8*)(hs + 8192 + kc * 512);
          acc0 = __builtin_amdgcn_mfma_f32_16x16x32_bf16(a0, wh[kc], acc0, 0, 0, 0);
          acc1 = __builtin_amdgcn_mfma_f32_16x16x32_bf16(a1, wh[kc], acc1, 0, 0, 0);
        }
      } else {
        // staged tile -> LDS (WG-coop, cuts agent-load LLC traffic 4x)
#pragma unroll
        for (int i = 0; i < 16; ++i) hbuf[i * 256 + tid] = stg[i];
        __syncthreads();
        const u16* hs = (const u16*)hbuf + lane * 8;
#pragma unroll
        for (int kc = 0; kc < 16; ++kc) {
          bf16x8 a0 = *(const bf16x8*)(hs + kc * 512);
          bf16x8 a1 = *(const bf16x8*)(hs + 8192 + kc * 512);
          acc0 = __builtin_amdgcn_mfma_f32_16x16x32_bf16(a0, wh[kc], acc0, 0, 0, 0);
          acc1 = __builtin_amdgcn_mfma_f32_16x16x32_bf16(a1, wh[kc], acc1, 0, 0, 0);
        }
      }
    }

    // ---- per-wave epilogue: D-frag -> gw transpose (intra-wave, lgkm only) ----
    {
      int c = lane & 15, rr = (lane >> 4) * 4;
#pragma unroll
      for (int r = 0; r < 4; ++r) {
        gw[(rr + r) * 20 + c]      = acc0[r];
        gw[(rr + r + 16) * 20 + c] = acc1[r];
      }
    }
    float4 g0 = *(const float4*)(gw + r0 * 20 + uw * 4);
    float4 g1 = *(const float4*)(gw + (r0 + 16) * 20 + uw * 4);
    float hh0, hh1;
    {
      float ii = sigm(g0.x + bb.x), ff = sigm(g0.y + bb.y);
      float gg = tanh_(g0.z + bb.z), oo = sigm(g0.w + bb.w);
      c0 = ff * c0 + ii * gg; hh0 = oo * tanh_(c0);
      ii = sigm(g1.x + bb.x); ff = sigm(g1.y + bb.y);
      gg = tanh_(g1.z + bb.z); oo = sigm(g1.w + bb.w);
      c1 = ff * c1 + ii * gg; hh1 = oo * tanh_(c1);
    }
    hst[r0 * 4 + uw]        = f2bf(hh0);
    hst[(r0 + 16) * 4 + uw] = f2bf(hh1);
    if (LAST && t == T_ - 1) {
      hlast[(size_t)(g * 32 + r0) * 512 + (jb + uw)]      = hh0;
      hlast[(size_t)(g * 32 + r0 + 16) * 512 + (jb + uw)] = hh1;
    }
    // lane<32: one 8B write-through store (row = lane, 4 units contiguous)
    if (lane < 32) {
      int b16l = lane >> 4, bl = lane & 15;
      size_t off = (size_t)(L1 ? (t & 3) : t) * 131072
                 + (size_t)((g * 2 + b16l) * 16 + kcb) * 512 + (qq * 16 + bl) * 8 + jjb;
      u64 v = *(const u64*)(hst + lane * 4);
      AS64((u64*)(Hdst + off), v);
    }
    asm volatile("s_waitcnt vmcnt(0)" ::: "memory");   // h at LLC before flag
    if (lane == 0) AS32(fown + widx, (unsigned int)(t + 1));
    if (L1) __syncthreads();   // hbuf WAR before next step's stage writes
  }
}

__global__ __launch_bounds__(256, 2) void lstm_fused(
    const u16* __restrict__ Wp0, const float* __restrict__ bp0,
    const u16* __restrict__ Wp1, const float* __restrict__ bp1,
    const u16* __restrict__ Xsw, u16* __restrict__ Hrot0,
    u16* __restrict__ Hring, float* __restrict__ hlast,
    unsigned int* __restrict__ sync)
{
  __shared__ __align__(16) float gwb[4][640];   // per-wave gate transpose (stride 20)
  __shared__ u64 hstb[4][32];                   // per-wave h staging (256B)
  __shared__ u64 hbuf[4096];                    // layer1 h1 tile (32KB)
  const int tid = threadIdx.x, lane = tid & 63, wave = tid >> 6;
  const int bid = blockIdx.x;
  float* gw = gwb[wave];
  u16*  hst = (u16*)hstb[wave];
  if (bid < 256) {
    const int g = bid & 7, widx = (bid >> 3) * 4 + wave;
    layer_loop<8, false, false>(Wp0, bp0, Xsw, Hrot0, nullptr,
                                sync + g * 128, nullptr,
                                g, widx, lane, tid, gw, hst, hbuf);
  } else {
    const int b2 = bid - 256;
    const int g = b2 & 7, widx = (b2 >> 3) * 4 + wave;
    layer_loop<16, true, true>(Wp1, bp1, Hrot0, Hring, hlast,
                               sync + 1024 + g * 128, sync + g * 128,
                               g, widx, lane, tid, gw, hst, hbuf);
  }
}

// ---------------- final projection y = hlast @ Wlin^T + b ----------------
__global__ void final_k(const float* __restrict__ hlast, const float* __restrict__ Wlin,
                        const float* __restrict__ blin, float* __restrict__ out)
{
  int b = blockIdx.x;
  int l = threadIdx.x;  // 64
  float s = 0.f;
#pragma unroll
  for (int j = l; j < 512; j += 64) s += hlast[(size_t)b * 512 + j] * Wlin[j];
#pragma unroll
  for (int off = 32; off > 0; off >>= 1) s += __shfl_down(s, off);
  if (l == 0) out[b] = s + blin[0];
}

extern "C" void kernel_launch(void* const* d_in, const int* in_sizes, int n_in,
                              void* d_out, int out_size, void* d_ws, size_t ws_size,
                              hipStream_t stream) {
  (void)in_sizes; (void)n_in; (void)out_size; (void)ws_size;
  const float* X    = (const float*)d_in[0];
  const float* Wih0 = (const float*)d_in[1];
  const float* Whh0 = (const float*)d_in[2];
  const float* bih0 = (const float*)d_in[3];
  const float* bhh0 = (const float*)d_in[4];
  const float* Wih1 = (const float*)d_in[5];
  const float* Whh1 = (const float*)d_in[6];
  const float* bih1 = (const float*)d_in[7];
  const float* bhh1 = (const float*)d_in[8];
  const float* Wlin = (const float*)d_in[9];
  const float* blin = (const float*)d_in[10];
  float* out = (float*)d_out;

  char* ws = (char*)d_ws;
  size_t o = 0;
  auto take = [&](size_t bytes) { char* p = ws + o; o = (o + bytes + 255) & ~(size_t)255; return p; };
  u16*   Wp0   = (u16*)take(2048ull * 768 * 2);              // 3 MB
  u16*   Wp1   = (u16*)take(2048ull * 1024 * 2);             // 4 MB
  float* bp0   = (float*)take(2048 * 4);
  float* bp1   = (float*)take(2048 * 4);
  u16*   Xsw   = (u16*)take((size_t)B_ * T_ * 256 * 2);      // 67 MB
  u16*   Hrot0 = (u16*)take((size_t)T_ * B_ * 512 * 2);      // 134 MB (full-depth h0)
  u16*   Hring = (u16*)take((size_t)4 * B_ * 512 * 2);       // 1 MB (h1, depth 4)
  float* hlast = (float*)take((size_t)B_ * 512 * 4);         // 512 KB
  unsigned int* sync = (unsigned int*)take(8192);            // 2 layers x 8 groups x 128 flags

  hipMemsetAsync(sync, 0, 8192, stream);

  pack_w<8> <<<768,  256, 0, stream>>>(Wih0, Whh0, bih0, bhh0, Wp0, bp0);
  pack_w<16><<<1024, 256, 0, stream>>>(Wih1, Whh1, bih1, bhh1, Wp1, bp1);
  pack_x    <<<16384,256, 0, stream>>>(X, Xsw);

  lstm_fused<<<512, 256, 0, stream>>>(Wp0, bp0, Wp1, bp1, Xsw, Hrot0, Hring, hlast, sync);
  final_k<<<256, 64, 0, stream>>>(hlast, Wlin, blin, out);
}